// Round 4
// baseline (703.287 us; speedup 1.0000x reference)
//
#include <hip/hip_runtime.h>

#define MM 128
#define NN 128
#define KK 128
#define NBATCH 4
#define ITERS 8
#define WIN 10
#define WSTRIDE 12
#define WSZ (WIN * WIN * WSTRIDE)  // 1200 floats per window
#define MNK (MM * NN * KK)
#define NSB 4                      // spatial sub-blocks per workgroup

typedef _Float16 h2 __attribute__((ext_vector_type(2)));

__device__ __forceinline__ float wave_sum(float v) {
  v += __shfl_xor(v, 32, 64);
  v += __shfl_xor(v, 16, 64);
  v += __shfl_xor(v, 8, 64);
  v += __shfl_xor(v, 4, 64);
  v += __shfl_xor(v, 2, 64);
  v += __shfl_xor(v, 1, 64);
  return v;
}

// Round-4 structure. Two changes vs the 294us round-0 kernel, both aimed at
// the register-footprint occupancy cap (rounds 0-3 all fit: occ == 512 /
// (VGPR+AGPR) because gfx950's unified file makes the 108 fp32 weights count
// against wave slots):
//  1) weights packed as fp16 pairs (56 VGPR instead of 108; S-compensation,
//     bias, rscale stay fp32). float(h16)*v+acc is the v_fma_mix pattern.
//  2) 512-thread workgroups = 4 spatial 8^3 sub-blocks (wave pair each),
//     identical lockstep code so the shared barriers are harmless. Also
//     defeats any per-SE workgroup-slot limit.
// Inner loop is round 0's verbatim: (1,2,2) micro-tile, single-buffered
// window, 2 barriers/iter -- the proven lowest DS-work/conflict pattern.
__global__ __launch_bounds__(512, 4) void gridnet_kernel(
    const float* __restrict__ weight, const float* __restrict__ bias,
    const float* __restrict__ rscale, const float* __restrict__ x,
    float* __restrict__ out) {
  // rows padded 10 -> 12 floats: float2-aligned, 2-way-bank-free
  __shared__ __align__(16) float Wl[NSB][WSZ];  // 19200 B
  __shared__ float red[NSB][8];

  const int t = threadIdx.x;
  const int sb = t >> 7;       // sub-block 0..3 (one wave pair)
  const int tl = t & 127;      // thread-in-sub-block
  const int r2 = tl & 3, q2 = (tl >> 2) & 3, p = tl >> 4;
  const int r0 = r2 * 2, q0 = q2 * 2;

  // XCD-bijective swizzle at WG level (1024 WGs % 8 == 0); sub-blocks of one
  // WG are bk-adjacent -> shared weight/x cache lines stay in one L2.
  const int lw = ((blockIdx.x & 7) << 7) | ((int)blockIdx.x >> 3);
  const int gb = lw * NSB + sb;  // global spatial block 0..4095
  const int bm = gb >> 8, bn = (gb >> 4) & 15, bk = gb & 15;
  const int gm0 = bm * 8, gn0 = bn * 8, gk0 = bk * 8;
  const int baseg = ((gm0 + p) * NN + (gn0 + q0)) * KK + (gk0 + r0);

  // ---- weights: packed fp16 pairs along o; wpk[dq][dr][o>>1][o&1] ----
  h2 wpk[2][2][14];
  float S[2][2] = {{0.f, 0.f}, {0.f, 0.f}};  // exact fp32 sums for -inv*mu*S
#pragma unroll
  for (int dq = 0; dq < 2; ++dq) {
#pragma unroll
    for (int oo = 0; oo < 14; ++oo) {
      const int o0 = 2 * oo, o1 = 2 * oo + 1;
      float2 a0 = *(const float2*)(weight + o0 * MNK + baseg + dq * KK);
      float2 a1 = make_float2(0.f, 0.f);
      if (o1 < 27)
        a1 = *(const float2*)(weight + o1 * MNK + baseg + dq * KK);
      wpk[dq][0][oo] = h2{(_Float16)a0.x, (_Float16)a1.x};
      wpk[dq][1][oo] = h2{(_Float16)a0.y, (_Float16)a1.y};
      S[dq][0] += a0.x + a1.x;
      S[dq][1] += a0.y + a1.y;
    }
  }
  float bia[2][2], rsc[2][2];
#pragma unroll
  for (int dq = 0; dq < 2; ++dq) {
    float2 bv = *(const float2*)(bias + baseg + dq * KK);
    bia[dq][0] = bv.x; bia[dq][1] = bv.y;
    float2 rv = *(const float2*)(rscale + baseg + dq * KK);
    rsc[dq][0] = rv.x; rsc[dq][1] = rv.y;
  }

  for (int b = 0; b < NBATCH; ++b) {
    __syncthreads();  // protect Wl/red from previous batch's readers
    // ---- load 10^3 window (zero-padded at grid boundary) into LDS ----
    float sA = 0.f, sAq = 0.f, sH = 0.f, sHq = 0.f;
    for (int idx = tl; idx < 1000; idx += 128) {
      int wp = idx / 100;
      int rem = idx - wp * 100;
      int wq = rem / 10;
      int wk = rem - wq * 10;
      int gm = gm0 - 1 + wp, gn = gn0 - 1 + wq, gk = gk0 - 1 + wk;
      float v = 0.0f;
      if ((unsigned)gm < 128u && (unsigned)gn < 128u && (unsigned)gk < 128u)
        v = x[((b * MM + gm) * NN + gn) * KK + gk];
      Wl[sb][(wp * WIN + wq) * WSTRIDE + wk] = v;
      sA += v; sAq += v * v;
      // halo (window shell) never changes across iterations: fold once
      if (wp == 0 || wp == 9 || wq == 0 || wq == 9 || wk == 0 || wk == 9) {
        sH += v; sHq += v * v;
      }
    }
    sA = wave_sum(sA); sAq = wave_sum(sAq);
    sH = wave_sum(sH); sHq = wave_sum(sHq);
    if ((tl & 63) == 0) {
      int wv_ = tl >> 6;
      red[sb][wv_ * 4 + 0] = sA; red[sb][wv_ * 4 + 1] = sAq;
      red[sb][wv_ * 4 + 2] = sH; red[sb][wv_ * 4 + 3] = sHq;
    }
    __syncthreads();
    float totS = red[sb][0] + red[sb][4], totQ = red[sb][1] + red[sb][5];
    const float hS = red[sb][2] + red[sb][6], hQ = red[sb][3] + red[sb][7];

    // own interior acts in registers (kept in sync with LDS)
    float a[2][2];
#pragma unroll
    for (int dq = 0; dq < 2; ++dq)
#pragma unroll
      for (int dr = 0; dr < 2; ++dr)
        a[dq][dr] = Wl[sb][((p + 1) * WIN + (q0 + dq + 1)) * WSTRIDE + (r0 + dr + 1)];

    float mu = totS * (1.0f / 1000.0f);
    float var = totQ * (1.0f / 1000.0f) - mu * mu;
    float inv = __builtin_amdgcn_rsqf(var + 1e-5f);

    for (int it = 0; it < ITERS; ++it) {
      // ---- locally-connected 3^3 conv on RAW acts (normalization folded) ----
      float acc[2][2] = {{0.f, 0.f}, {0.f, 0.f}};
#pragma unroll
      for (int i = 0; i < 3; ++i) {
        float v[4][4];
#pragma unroll
        for (int jj = 0; jj < 4; ++jj) {
          const float* bp = &Wl[sb][((p + i) * WIN + (q0 + jj)) * WSTRIDE + r0];
          float2 u0 = *(const float2*)bp;
          float2 u1 = *(const float2*)(bp + 2);
          v[jj][0] = u0.x; v[jj][1] = u0.y; v[jj][2] = u1.x; v[jj][3] = u1.y;
        }
#pragma unroll
        for (int j = 0; j < 3; ++j)
#pragma unroll
          for (int kc = 0; kc < 3; ++kc) {
            const int o = i * 9 + j * 3 + kc;
            const int oh = o >> 1, ol = o & 1;  // compile-time
            const float w00 = (float)wpk[0][0][oh][ol];
            const float w01 = (float)wpk[0][1][oh][ol];
            const float w10 = (float)wpk[1][0][oh][ol];
            const float w11 = (float)wpk[1][1][oh][ol];
            acc[0][0] += w00 * v[0 + j][kc];
            acc[0][1] += w01 * v[0 + j][kc + 1];
            acc[1][0] += w10 * v[1 + j][kc];
            acc[1][1] += w11 * v[1 + j][kc + 1];
          }
      }
      // acc_final = bias + inv*(conv_raw) - inv*mu*(sum of 27 weights)
      const float im = inv * mu;
#pragma unroll
      for (int dq = 0; dq < 2; ++dq)
#pragma unroll
        for (int dr = 0; dr < 2; ++dr) {
          float z = bia[dq][dr] + inv * acc[dq][dr] - im * S[dq][dr];
          float e = __expf(-z);
          float sg = __builtin_amdgcn_rcpf(1.0f + e);  // sigmoid(z)
          a[dq][dr] += rsc[dq][dr] * (z * sg);          // residual silu
        }
      if (it < ITERS - 1) {
        __syncthreads();  // all conv reads done before anyone writes
#pragma unroll
        for (int dq = 0; dq < 2; ++dq)
#pragma unroll
          for (int dr = 0; dr < 2; ++dr)
            Wl[sb][((p + 1) * WIN + (q0 + dq + 1)) * WSTRIDE + (r0 + dr + 1)] = a[dq][dr];
        float ls = a[0][0] + a[0][1] + a[1][0] + a[1][1];
        float lq = a[0][0] * a[0][0] + a[0][1] * a[0][1] +
                   a[1][0] * a[1][0] + a[1][1] * a[1][1];
        ls = wave_sum(ls); lq = wave_sum(lq);
        if ((tl & 63) == 0) {
          red[sb][(tl >> 6) * 2 + 0] = ls;
          red[sb][(tl >> 6) * 2 + 1] = lq;
        }
        __syncthreads();  // partials ready AND writes visible for next iter
        float tS = red[sb][0] + red[sb][2] + hS;
        float tQ = red[sb][1] + red[sb][3] + hQ;
        mu = tS * (1.0f / 1000.0f);
        var = tQ * (1.0f / 1000.0f) - mu * mu;
        inv = __builtin_amdgcn_rsqf(var + 1e-5f);
      }
    }
    // ---- write final interior from registers ----
    const int baseo = ((b * MM + gm0 + p) * NN + (gn0 + q0)) * KK + (gk0 + r0);
#pragma unroll
    for (int dq = 0; dq < 2; ++dq) {
      float2 ov; ov.x = a[dq][0]; ov.y = a[dq][1];
      *(float2*)(out + baseo + dq * KK) = ov;
    }
  }
}

extern "C" void kernel_launch(void* const* d_in, const int* in_sizes, int n_in,
                              void* d_out, int out_size, void* d_ws, size_t ws_size,
                              hipStream_t stream) {
  const float* weight = (const float*)d_in[0];
  const float* bias   = (const float*)d_in[1];
  const float* rscale = (const float*)d_in[2];
  const float* x      = (const float*)d_in[3];
  // d_in[4] = inner_iterations (8), d_in[5] = block_size (8): fixed by harness
  float* out = (float*)d_out;
  gridnet_kernel<<<dim3(1024), dim3(512), 0, stream>>>(
      weight, bias, rscale, x, out);
}